// Round 5
// baseline (28.672 us; speedup 1.0000x reference)
//
#include <hip/hip_runtime.h>

// MultiEmbedding: out[n,s,:] = sum_l weight[l, x[n,l,s], :]
// weight: [L=8, K=1024, D=512] f32, x: [N=8, L=8, S=4096] int32
// out: [N=8, S=4096, D=512] f32
//
// Layout win (round 1): D split into 8 chunks of 64 floats; chunk = blockIdx%8
// pins each chunk to one XCD whose 4 MiB L2 holds that chunk's weight slice
// (2 MiB) -> weight fetched from HBM ~once. NT stores keep the 64 MB write
// stream from evicting it.
// This round (2nd resubmit after infra failures): fatter blocks (2048 instead
// of 16384) with 4x-unrolled row loop and 2 independent row streams per
// thread -> amortize block setup, deepen MLP.

#define LVL 8
#define KTOK 1024
#define DIM 512
#define SEQ 4096
#define NB 8
#define CHUNK 64
#define NCHUNK (DIM / CHUNK)      // 8 chunks, one per XCD
#define ROWS_PER_BLOCK 128
#define BLOCKS_PER_CHUNK ((NB * SEQ) / ROWS_PER_BLOCK)  // 256

typedef float f4 __attribute__((ext_vector_type(4)));

__global__ __launch_bounds__(256) void multi_embed_kernel(
    const int* __restrict__ x, const float* __restrict__ w, float* __restrict__ out) {
  const int tid    = threadIdx.x;
  const int chunk  = blockIdx.x & (NCHUNK - 1);   // XCD-pinned D-chunk
  const int blk    = blockIdx.x >> 3;             // 0..255 within chunk
  const int rlocal = tid >> 4;                    // 0..15 row slot
  const int slot   = tid & 15;                    // float4 slot within chunk
  const int dbase  = chunk * CHUNK + slot * 4;

  const int baserow = blk * ROWS_PER_BLOCK;       // flat (n*SEQ + s), n uniform
  const int n     = baserow >> 12;
  const int sbase = baserow & (SEQ - 1);

  const int*   xp = x + n * (LVL * SEQ);
  const float* wp = w + dbase;
  float*       op = out + (size_t)baserow * DIM + dbase;

#pragma unroll
  for (int it = 0; it < ROWS_PER_BLOCK / 32; ++it) {
    const int s0 = sbase + it * 32 + rlocal;
    const int s1 = s0 + 16;

    int i0[LVL], i1[LVL];
#pragma unroll
    for (int l = 0; l < LVL; ++l) {
      i0[l] = xp[l * SEQ + s0];
      i1[l] = xp[l * SEQ + s1];
    }

    f4 a0 = {0.f, 0.f, 0.f, 0.f};
    f4 a1 = {0.f, 0.f, 0.f, 0.f};
#pragma unroll
    for (int l = 0; l < LVL; ++l) {
      a0 += *reinterpret_cast<const f4*>(wp + (size_t)(l * KTOK + i0[l]) * DIM);
      a1 += *reinterpret_cast<const f4*>(wp + (size_t)(l * KTOK + i1[l]) * DIM);
    }

    __builtin_nontemporal_store(
        a0, reinterpret_cast<f4*>(op + (size_t)(it * 32 + rlocal) * DIM));
    __builtin_nontemporal_store(
        a1, reinterpret_cast<f4*>(op + (size_t)(it * 32 + rlocal + 16) * DIM));
  }
}

extern "C" void kernel_launch(void* const* d_in, const int* in_sizes, int n_in,
                              void* d_out, int out_size, void* d_ws, size_t ws_size,
                              hipStream_t stream) {
  const int*   x = (const int*)d_in[0];    // [N, L, S]
  const float* w = (const float*)d_in[1];  // [L, K, D]
  float*     out = (float*)d_out;          // [N, S, D]

  multi_embed_kernel<<<dim3(BLOCKS_PER_CHUNK * NCHUNK), dim3(256), 0, stream>>>(x, w, out);
}